// Round 1
// baseline (2551.480 us; speedup 1.0000x reference)
//
#include <hip/hip_runtime.h>

#define NN    20000
#define NE    150000
#define HD    256
#define NT    4
#define NR    8
#define NH    8
#define DKq   32
#define NL    2
#define MAXL  240
#define INV_SQRT_DK 0.17677669529663687f

// ---------- helpers: order-preserving float<->uint for atomicMax ----------
__device__ __forceinline__ unsigned f2ord(float v){
    unsigned u = __float_as_uint(v);
    return (u & 0x80000000u) ? ~u : (u | 0x80000000u);
}
__device__ __forceinline__ float ord2f(unsigned k){
    return __uint_as_float((k & 0x80000000u) ? (k ^ 0x80000000u) : ~k);
}

// ---------- bucket building (counting sort by type / relation) ----------
__global__ void k_init_counts(int* ncnt, int* ecnt){
    int i = threadIdx.x;
    if (i < NT) ncnt[i] = 0;
    if (i < NR) ecnt[i] = 0;
}
__global__ void k_count(const int* __restrict__ ntype, const int* __restrict__ etype,
                        int* ncnt, int* ecnt){
    int i = blockIdx.x*blockDim.x + threadIdx.x;
    if (i < NN) atomicAdd(&ncnt[ntype[i]], 1);
    if (i < NE) atomicAdd(&ecnt[etype[i]], 1);
}
__global__ void k_offsets(const int* __restrict__ ncnt, const int* __restrict__ ecnt,
                          int* noff, int* eoff, int* ncur, int* ecur){
    noff[0]=0; for(int t=0;t<NT;t++){ noff[t+1]=noff[t]+ncnt[t]; ncur[t]=0; }
    eoff[0]=0; for(int r=0;r<NR;r++){ eoff[r+1]=eoff[r]+ecnt[r]; ecur[r]=0; }
}
__global__ void k_scatter(const int* __restrict__ ntype, const int* __restrict__ etype,
                          const int* __restrict__ noff, const int* __restrict__ eoff,
                          int* ncur, int* ecur, int* nbucket, int* ebucket){
    int i = blockIdx.x*blockDim.x + threadIdx.x;
    if (i < NN){ int t=ntype[i]; nbucket[noff[t] + atomicAdd(&ncur[t],1)] = i; }
    if (i < NE){ int r=etype[i]; ebucket[eoff[r] + atomicAdd(&ecur[r],1)] = i; }
}

// ---------- typed GEMM: out[node] = act( in[node] @ W[type] + b[type] ) ----------
// mode 0: plain+bias; mode 1: tanh; mode 2: skip-combine with xold
__global__ __launch_bounds__(256) void k_typed_gemm(
    const float* __restrict__ in, const float* __restrict__ Wb, const float* __restrict__ bb,
    float* __restrict__ out, const int* __restrict__ nbucket, const int* __restrict__ noff,
    int mode, const float* __restrict__ skipv, const float* __restrict__ xold)
{
    const int t = blockIdx.z;
    const int start = noff[t];
    const int cnt = noff[t+1] - start;
    const int rowTile = blockIdx.y;
    if (rowTile*64 >= cnt) return;
    const int colTile = blockIdx.x;
    const int tid = threadIdx.x;
    const int tx = tid & 15, ty = tid >> 4;

    __shared__ float As[16][68];   // [kk][m], padded stride 68 (272B, 16B-aligned rows)
    __shared__ float Bs[16][68];   // [kk][j]

    const int lm = tid >> 2;            // A-load row 0..63
    const int lk = (tid & 3) << 2;      // A-load k offset {0,4,8,12}
    int anode = -1;
    { int gr = rowTile*64 + lm; if (gr < cnt) anode = nbucket[start + gr]; }
    const int bj = tid & 63;            // B-load col
    const int bk = (tid >> 6) << 2;     // B-load k base {0,4,8,12}
    const float* Wt = Wb + (size_t)t*HD*HD + colTile*64;

    float acc[4][4] = {};
    for (int k0 = 0; k0 < HD; k0 += 16){
        float4 av = make_float4(0.f,0.f,0.f,0.f);
        if (anode >= 0)
            av = *reinterpret_cast<const float4*>(&in[(size_t)anode*HD + k0 + lk]);
        As[lk+0][lm]=av.x; As[lk+1][lm]=av.y; As[lk+2][lm]=av.z; As[lk+3][lm]=av.w;
        #pragma unroll
        for (int i=0;i<4;i++)
            Bs[bk+i][bj] = Wt[(size_t)(k0+bk+i)*HD + bj];
        __syncthreads();
        #pragma unroll
        for (int kk=0;kk<16;kk++){
            float4 a4 = *reinterpret_cast<const float4*>(&As[kk][ty<<2]);
            float4 b4 = *reinterpret_cast<const float4*>(&Bs[kk][tx<<2]);
            acc[0][0]=fmaf(a4.x,b4.x,acc[0][0]); acc[0][1]=fmaf(a4.x,b4.y,acc[0][1]);
            acc[0][2]=fmaf(a4.x,b4.z,acc[0][2]); acc[0][3]=fmaf(a4.x,b4.w,acc[0][3]);
            acc[1][0]=fmaf(a4.y,b4.x,acc[1][0]); acc[1][1]=fmaf(a4.y,b4.y,acc[1][1]);
            acc[1][2]=fmaf(a4.y,b4.z,acc[1][2]); acc[1][3]=fmaf(a4.y,b4.w,acc[1][3]);
            acc[2][0]=fmaf(a4.z,b4.x,acc[2][0]); acc[2][1]=fmaf(a4.z,b4.y,acc[2][1]);
            acc[2][2]=fmaf(a4.z,b4.z,acc[2][2]); acc[2][3]=fmaf(a4.z,b4.w,acc[2][3]);
            acc[3][0]=fmaf(a4.w,b4.x,acc[3][0]); acc[3][1]=fmaf(a4.w,b4.y,acc[3][1]);
            acc[3][2]=fmaf(a4.w,b4.z,acc[3][2]); acc[3][3]=fmaf(a4.w,b4.w,acc[3][3]);
        }
        __syncthreads();
    }
    float sk = 0.f;
    if (mode == 2) sk = 1.f/(1.f + expf(-skipv[t]));
    const int c0 = colTile*64 + (tx<<2);
    #pragma unroll
    for (int i=0;i<4;i++){
        int gr = rowTile*64 + (ty<<2) + i;
        if (gr >= cnt) continue;
        int node = nbucket[start + gr];
        float4 o;
        o.x = acc[i][0] + bb[t*HD + c0 + 0];
        o.y = acc[i][1] + bb[t*HD + c0 + 1];
        o.z = acc[i][2] + bb[t*HD + c0 + 2];
        o.w = acc[i][3] + bb[t*HD + c0 + 3];
        if (mode == 1){
            o.x = tanhf(o.x); o.y = tanhf(o.y); o.z = tanhf(o.z); o.w = tanhf(o.w);
        } else if (mode == 2){
            const float4 xo = *reinterpret_cast<const float4*>(&xold[(size_t)node*HD + c0]);
            o.x = o.x*sk + xo.x*(1.f-sk);
            o.y = o.y*sk + xo.y*(1.f-sk);
            o.z = o.z*sk + xo.z*(1.f-sk);
            o.w = o.w*sk + xo.w*(1.f-sk);
        }
        *reinterpret_cast<float4*>(&out[(size_t)node*HD + c0]) = o;
    }
}

// ---------- small row GEMM: C[row, ty] = A[row] @ W[ty] (+bias) ----------
__global__ __launch_bounds__(256) void k_row_gemm(
    const float* __restrict__ A, const float* __restrict__ Wb, const float* __restrict__ bias,
    float* __restrict__ C, int c_stride)
{
    const int row = blockIdx.x, ty = blockIdx.y, d = threadIdx.x;
    const float* W = Wb + (size_t)ty*HD*HD;
    __shared__ float ar[HD];
    ar[d] = A[(size_t)row*HD + d];
    __syncthreads();
    float acc = bias ? bias[d] : 0.f;
    #pragma unroll 8
    for (int k=0;k<HD;k++) acc = fmaf(ar[k], W[(size_t)k*HD + d], acc);
    C[(size_t)row*c_stride + ty*HD + d] = acc;
}

// ---------- edge attention scores: att_e[e,h] = (q . (k @ A_rh)) * pri / sqrt(dk) ----------
// wave-per-edge; edges pre-bucketed by relation; rel_att[r] staged in LDS.
__global__ __launch_bounds__(256) void k_edge_att(
    const float* __restrict__ q0, const float* __restrict__ k0, const float* __restrict__ Kc,
    const float* __restrict__ relA, const float* __restrict__ relP,
    const int* __restrict__ ei, const int* __restrict__ etime, const int* __restrict__ ntype,
    const int* __restrict__ ebucket, const int* __restrict__ eoff,
    float* __restrict__ att_e)
{
    const int r = blockIdx.y;
    const int start = eoff[r], cnt = eoff[r+1]-start;
    if ((int)blockIdx.x*64 >= cnt) return;
    const int tid = threadIdx.x;
    const int wave = tid >> 6, lane = tid & 63;
    __shared__ float Ash[NH*DKq*DKq];
    __shared__ float psh[NH];
    __shared__ float rq[4][HD];
    __shared__ float rk[4][HD];
    for (int i = tid; i < NH*DKq*DKq; i += 256) Ash[i] = relA[(size_t)r*NH*DKq*DKq + i];
    if (tid < NH) psh[tid] = relP[r*NH + tid] * INV_SQRT_DK;
    __syncthreads();
    const int h2 = lane >> 5, c = lane & 31;
    const int base = blockIdx.x*64 + wave*16;
    for (int it = 0; it < 16; it++){
        const int idx = base + it;
        if (idx >= cnt) break;
        const int e = ebucket[start + idx];
        const int src = ei[e], tgt = ei[NE + e];
        const int tm = etime[e], st = ntype[src];
        const float* qrow = q0 + (size_t)tgt*HD;
        const float* krow = k0 + (size_t)src*HD;
        const float* crow = Kc + (size_t)(tm*NT + st)*HD;
        #pragma unroll
        for (int i=0;i<4;i++){
            int cc = lane + i*64;
            rq[wave][cc] = qrow[cc];
            rk[wave][cc] = krow[cc] + crow[cc];
        }
        #pragma unroll
        for (int hh=0; hh<4; hh++){
            const int h = hh*2 + h2;
            float kr = 0.f;
            #pragma unroll
            for (int dd=0; dd<DKq; dd++)
                kr = fmaf(Ash[h*DKq*DKq + dd*DKq + c], rk[wave][h*DKq + dd], kr);
            float prod = rq[wave][h*DKq + c] * kr;
            #pragma unroll
            for (int m=16;m>=1;m>>=1) prod += __shfl_xor(prod, m);
            if (c == 0) att_e[(size_t)e*NH + h] = prod * psh[h];
        }
    }
}

// ---------- edge message + aggregation: agg[tgt] += alpha * (v @ M_rh) ----------
__global__ __launch_bounds__(256) void k_edge_msg(
    const float* __restrict__ v0, const float* __restrict__ Vc,
    const float* __restrict__ relM, const float* __restrict__ alpha,
    const int* __restrict__ ei, const int* __restrict__ etime, const int* __restrict__ ntype,
    const int* __restrict__ ebucket, const int* __restrict__ eoff,
    float* __restrict__ agg)
{
    const int r = blockIdx.y;
    const int start = eoff[r], cnt = eoff[r+1]-start;
    if ((int)blockIdx.x*64 >= cnt) return;
    const int tid = threadIdx.x;
    const int wave = tid >> 6, lane = tid & 63;
    __shared__ float Msh[NH*DKq*DKq];
    __shared__ float rv[4][HD];
    for (int i = tid; i < NH*DKq*DKq; i += 256) Msh[i] = relM[(size_t)r*NH*DKq*DKq + i];
    __syncthreads();
    const int h2 = lane >> 5, c = lane & 31;
    const int base = blockIdx.x*64 + wave*16;
    for (int it = 0; it < 16; it++){
        const int idx = base + it;
        if (idx >= cnt) break;
        const int e = ebucket[start + idx];
        const int src = ei[e], tgt = ei[NE + e];
        const int tm = etime[e], st = ntype[src];
        const float* vrow = v0 + (size_t)src*HD;
        const float* crow = Vc + (size_t)(tm*NT + st)*HD;
        #pragma unroll
        for (int i=0;i<4;i++){
            int cc = lane + i*64;
            rv[wave][cc] = vrow[cc] + crow[cc];
        }
        #pragma unroll
        for (int hh=0; hh<4; hh++){
            const int h = hh*2 + h2;
            float vr = 0.f;
            #pragma unroll
            for (int dd=0; dd<DKq; dd++)
                vr = fmaf(Msh[h*DKq*DKq + dd*DKq + c], rv[wave][h*DKq + dd], vr);
            float al = alpha[(size_t)e*NH + h];
            atomicAdd(&agg[(size_t)tgt*HD + h*DKq + c], al*vr);
        }
    }
}

// ---------- segment softmax ----------
__global__ void k_seg_max(const float* __restrict__ att_e, const int* __restrict__ ei,
                          unsigned* __restrict__ segmax){
    int i = blockIdx.x*blockDim.x + threadIdx.x;
    if (i >= NE*NH) return;
    int e = i >> 3, h = i & 7;
    atomicMax(&segmax[(size_t)ei[NE+e]*NH + h], f2ord(att_e[i]));
}
__global__ void k_seg_expsum(float* __restrict__ att_e, const int* __restrict__ ei,
                             const unsigned* __restrict__ segmax, float* __restrict__ segsum){
    int i = blockIdx.x*blockDim.x + threadIdx.x;
    if (i >= NE*NH) return;
    int e = i >> 3, h = i & 7;
    int t = ei[NE+e];
    float m = ord2f(segmax[(size_t)t*NH + h]);
    float ex = expf(att_e[i] - m);
    att_e[i] = ex;
    atomicAdd(&segsum[(size_t)t*NH + h], ex);
}
__global__ void k_seg_alpha(const float* __restrict__ att_e, const int* __restrict__ ei,
                            const float* __restrict__ segsum, float* __restrict__ alpha,
                            float* __restrict__ out_att){
    int i = blockIdx.x*blockDim.x + threadIdx.x;
    if (i >= NE*NH) return;
    int e = i >> 3, h = i & 7;
    int t = ei[NE+e];
    float a = att_e[i] / segsum[(size_t)t*NH + h];
    alpha[i] = a;
    if (out_att) out_att[i] = a;
}

// ---------- misc elementwise ----------
__global__ void k_init_seg(unsigned* __restrict__ segmax, float* __restrict__ segsum,
                           float* __restrict__ agg){
    int i = blockIdx.x*blockDim.x + threadIdx.x;
    if (i < NN*HD) agg[i] = 0.f;
    if (i < NN*NH){ segmax[i] = 0u; segsum[i] = 0.f; }
}
__global__ void k_gelu(float* __restrict__ agg){
    int i = blockIdx.x*blockDim.x + threadIdx.x;
    if (i >= NN*HD) return;
    float x = agg[i];
    agg[i] = 0.5f*x*(1.f + erff(x*0.70710678118654752f));
}
__global__ void k_copy(const float* __restrict__ s, float* __restrict__ d, int n){
    int i = blockIdx.x*blockDim.x + threadIdx.x;
    if (i < n) d[i] = s[i];
}

extern "C" void kernel_launch(void* const* d_in, const int* in_sizes, int n_in,
                              void* d_out, int out_size, void* d_ws, size_t ws_size,
                              hipStream_t stream)
{
    const float* node_feature = (const float*)d_in[0];
    const int*   node_type    = (const int*)d_in[1];
    const int*   edge_time    = (const int*)d_in[2];
    const int*   edge_index   = (const int*)d_in[3];  // [2,E]
    const int*   edge_type    = (const int*)d_in[4];
    const float* adapt_W = (const float*)d_in[5];
    const float* adapt_b = (const float*)d_in[6];
    const float* k_W = (const float*)d_in[7];
    const float* k_b = (const float*)d_in[8];
    const float* q_W = (const float*)d_in[9];
    const float* q_b = (const float*)d_in[10];
    const float* v_W = (const float*)d_in[11];
    const float* v_b = (const float*)d_in[12];
    const float* a_W = (const float*)d_in[13];
    const float* a_b = (const float*)d_in[14];
    const float* rel_pri = (const float*)d_in[15];
    const float* rel_att = (const float*)d_in[16];
    const float* rel_msg = (const float*)d_in[17];
    const float* skip  = (const float*)d_in[18];
    const float* rte_W = (const float*)d_in[19];
    const float* rte_b = (const float*)d_in[20];
    const float* rte_emb = (const float*)d_in[21];

    char* wp = (char*)d_ws;
    auto alloc_f = [&](size_t n)->float*{ float* p=(float*)wp; wp += n*sizeof(float); return p; };
    auto alloc_i = [&](size_t n)->int*  { int*   p=(int*)wp;   wp += n*sizeof(int);   return p; };
    float* xA    = alloc_f((size_t)NN*HD);
    float* xB    = alloc_f((size_t)NN*HD);
    float* q0    = alloc_f((size_t)NN*HD);
    float* k0    = alloc_f((size_t)NN*HD);
    float* v0    = alloc_f((size_t)NN*HD);
    float* agg   = alloc_f((size_t)NN*HD);
    float* att_e = alloc_f((size_t)NE*NH);
    float* alpha = alloc_f((size_t)NE*NH);
    float* segsum= alloc_f((size_t)NN*NH);
    float* rteP  = alloc_f((size_t)MAXL*HD);
    float* Kc    = alloc_f((size_t)MAXL*NT*HD);
    float* Vc    = alloc_f((size_t)MAXL*NT*HD);
    unsigned* segmax = (unsigned*)alloc_i((size_t)NN*NH);
    int* nbucket = alloc_i(NN);
    int* ebucket = alloc_i(NE);
    int* ncnt = alloc_i(8);  int* ecnt = alloc_i(8);
    int* noff = alloc_i(8);  int* eoff = alloc_i(16);
    int* ncur = alloc_i(8);  int* ecur = alloc_i(8);

    float* out_att = (float*)d_out;
    float* out_x   = (float*)d_out + (size_t)NE*NH;

    const int gCnt = (NE + 255)/256;
    const dim3 gT(4, (NN+63)/64, NT);
    const dim3 gE((NE+63)/64, NR);
    const int gEH = (NE*NH + 255)/256;
    const int gNH = (NN*HD + 255)/256;

    // buckets (rebuilt every call; deterministic outputs)
    k_init_counts<<<1,64,0,stream>>>(ncnt, ecnt);
    k_count<<<gCnt,256,0,stream>>>(node_type, edge_type, ncnt, ecnt);
    k_offsets<<<1,1,0,stream>>>(ncnt, ecnt, noff, eoff, ncur, ecur);
    k_scatter<<<gCnt,256,0,stream>>>(node_type, edge_type, noff, eoff, ncur, ecur, nbucket, ebucket);

    // adapt: x = tanh(node_feature @ adapt_W[t] + b)
    k_typed_gemm<<<gT,256,0,stream>>>(node_feature, adapt_W, adapt_b, xA, nbucket, noff,
                                      1, nullptr, nullptr);

    const float* x_in = xA;
    float* x_out = xB;
    for (int l = 0; l < NL; l++){
        // RTE projection table [240,256] and per-(time,type) K/V corrections [240*4,256]
        k_row_gemm<<<dim3(MAXL,1),256,0,stream>>>(rte_emb, rte_W + (size_t)l*HD*HD,
                                                  rte_b + (size_t)l*HD, rteP, HD);
        k_row_gemm<<<dim3(MAXL,NT),256,0,stream>>>(rteP, k_W + (size_t)l*NT*HD*HD, nullptr, Kc, NT*HD);
        k_row_gemm<<<dim3(MAXL,NT),256,0,stream>>>(rteP, v_W + (size_t)l*NT*HD*HD, nullptr, Vc, NT*HD);
        // node-level q0/k0/v0
        k_typed_gemm<<<gT,256,0,stream>>>(x_in, q_W + (size_t)l*NT*HD*HD, q_b + (size_t)l*NT*HD,
                                          q0, nbucket, noff, 0, nullptr, nullptr);
        k_typed_gemm<<<gT,256,0,stream>>>(x_in, k_W + (size_t)l*NT*HD*HD, k_b + (size_t)l*NT*HD,
                                          k0, nbucket, noff, 0, nullptr, nullptr);
        k_typed_gemm<<<gT,256,0,stream>>>(x_in, v_W + (size_t)l*NT*HD*HD, v_b + (size_t)l*NT*HD,
                                          v0, nbucket, noff, 0, nullptr, nullptr);
        k_init_seg<<<gNH,256,0,stream>>>(segmax, segsum, agg);
        // attention scores
        k_edge_att<<<gE,256,0,stream>>>(q0, k0, Kc,
                                        rel_att + (size_t)l*NR*NH*DKq*DKq, rel_pri + (size_t)l*NR*NH,
                                        edge_index, edge_time, node_type, ebucket, eoff, att_e);
        // segment softmax over target nodes
        k_seg_max<<<gEH,256,0,stream>>>(att_e, edge_index, segmax);
        k_seg_expsum<<<gEH,256,0,stream>>>(att_e, edge_index, segmax, segsum);
        k_seg_alpha<<<gEH,256,0,stream>>>(att_e, edge_index, segsum, alpha,
                                          (l == NL-1) ? out_att : nullptr);
        // messages + aggregation
        k_edge_msg<<<gE,256,0,stream>>>(v0, Vc,
                                        rel_msg + (size_t)l*NR*NH*DKq*DKq, alpha,
                                        edge_index, edge_time, node_type, ebucket, eoff, agg);
        k_gelu<<<gNH,256,0,stream>>>(agg);
        // output transform + skip
        k_typed_gemm<<<gT,256,0,stream>>>(agg, a_W + (size_t)l*NT*HD*HD, a_b + (size_t)l*NT*HD,
                                          x_out, nbucket, noff, 2, skip + (size_t)l*NT, x_in);
        float* tmp = (float*)x_in; x_in = x_out; x_out = tmp;
    }
    k_copy<<<gNH,256,0,stream>>>(x_in, out_x, NN*HD);
}

// Round 2
// 1333.823 us; speedup vs baseline: 1.9129x; 1.9129x over previous
//
#include <hip/hip_runtime.h>

#define NN    20000
#define NE    150000
#define HD    256
#define NT    4
#define NR    8
#define NH    8
#define DKq   32
#define NL    2
#define MAXL  240
#define HBLK  256
#define INV_SQRT_DK 0.17677669529663687f

// ---------- helpers: order-preserving float<->uint for atomicMax ----------
__device__ __forceinline__ unsigned f2ord(float v){
    unsigned u = __float_as_uint(v);
    return (u & 0x80000000u) ? ~u : (u | 0x80000000u);
}
__device__ __forceinline__ float ord2f(unsigned k){
    return __uint_as_float((k & 0x80000000u) ? (k ^ 0x80000000u) : ~k);
}

// ---------- bucket building: block-local histogram radix pass ----------
// Pass 1: per-block LDS histogram (LDS atomics only)
__global__ __launch_bounds__(256) void k_hist(
    const int* __restrict__ ntype, const int* __restrict__ etype,
    int* __restrict__ nhist, int* __restrict__ ehist)
{
    __shared__ int h[NT+NR];
    const int tid = threadIdx.x, b = blockIdx.x;
    if (tid < NT+NR) h[tid] = 0;
    __syncthreads();
    const int cn = (NN + HBLK-1)/HBLK;      // 79
    const int ce = (NE + HBLK-1)/HBLK;      // 586
    const int nEnd = min((b+1)*cn, NN);
    const int eEnd = min((b+1)*ce, NE);
    for (int i = b*cn + tid; i < nEnd; i += 256) atomicAdd(&h[ntype[i]], 1);
    for (int i = b*ce + tid; i < eEnd; i += 256) atomicAdd(&h[NT + etype[i]], 1);
    __syncthreads();
    if (tid < NT)            nhist[b*NT + tid] = h[tid];
    else if (tid < NT+NR)    ehist[b*NR + (tid-NT)] = h[tid];
}

// Pass 2: tiny serial scan -> bucket offsets + per-block bases
__global__ void k_scan(const int* __restrict__ nhist, const int* __restrict__ ehist,
                       int* __restrict__ noff, int* __restrict__ eoff,
                       int* __restrict__ nbase, int* __restrict__ ebase)
{
    __shared__ int tot[NT+NR];
    const int tid = threadIdx.x;
    if (tid < NT){
        int s = 0;
        for (int b = 0; b < HBLK; b++) s += nhist[b*NT + tid];
        tot[tid] = s;
    } else if (tid < NT+NR){
        const int r = tid - NT; int s = 0;
        for (int b = 0; b < HBLK; b++) s += ehist[b*NR + r];
        tot[tid] = s;
    }
    __syncthreads();
    if (tid == 0){
        noff[0]=0; for (int t=0;t<NT;t++) noff[t+1]=noff[t]+tot[t];
        eoff[0]=0; for (int r=0;r<NR;r++) eoff[r+1]=eoff[r]+tot[NT+r];
    }
    if (tid < NT){
        int base = 0; for (int t=0;t<tid;t++) base += tot[t];
        int run = 0;
        for (int b=0;b<HBLK;b++){ nbase[b*NT+tid] = base + run; run += nhist[b*NT+tid]; }
    } else if (tid < NT+NR){
        const int r = tid - NT;
        int base = 0; for (int t=0;t<r;t++) base += tot[NT+t];
        int run = 0;
        for (int b=0;b<HBLK;b++){ ebase[b*NR+r] = base + run; run += ehist[b*NR+r]; }
    }
}

// Pass 3: scatter with LDS cursors (no global atomics)
__global__ __launch_bounds__(256) void k_scatter2(
    const int* __restrict__ ntype, const int* __restrict__ etype,
    const int* __restrict__ nbase, const int* __restrict__ ebase,
    int* __restrict__ nbucket, int* __restrict__ ebucket)
{
    __shared__ int cur[NT+NR];
    const int tid = threadIdx.x, b = blockIdx.x;
    if (tid < NT)            cur[tid] = nbase[b*NT + tid];
    else if (tid < NT+NR)    cur[tid] = ebase[b*NR + (tid-NT)];
    __syncthreads();
    const int cn = (NN + HBLK-1)/HBLK;
    const int ce = (NE + HBLK-1)/HBLK;
    const int nEnd = min((b+1)*cn, NN);
    const int eEnd = min((b+1)*ce, NE);
    for (int i = b*cn + tid; i < nEnd; i += 256)
        nbucket[atomicAdd(&cur[ntype[i]], 1)] = i;
    for (int i = b*ce + tid; i < eEnd; i += 256)
        ebucket[atomicAdd(&cur[NT + etype[i]], 1)] = i;
}

// ---------- typed GEMM: out[node] = act( in[node] @ W[type] + b[type] ) ----------
// mode 0: plain+bias; mode 1: tanh; mode 2: skip-combine with xold
__global__ __launch_bounds__(256) void k_typed_gemm(
    const float* __restrict__ in, const float* __restrict__ Wb, const float* __restrict__ bb,
    float* __restrict__ out, const int* __restrict__ nbucket, const int* __restrict__ noff,
    int mode, const float* __restrict__ skipv, const float* __restrict__ xold)
{
    const int t = blockIdx.z;
    const int start = noff[t];
    const int cnt = noff[t+1] - start;
    const int rowTile = blockIdx.y;
    if (rowTile*64 >= cnt) return;
    const int colTile = blockIdx.x;
    const int tid = threadIdx.x;
    const int tx = tid & 15, ty = tid >> 4;

    __shared__ float As[16][68];   // [kk][m], padded stride 68
    __shared__ float Bs[16][68];   // [kk][j]

    const int lm = tid >> 2;            // A-load row 0..63
    const int lk = (tid & 3) << 2;      // A-load k offset {0,4,8,12}
    int anode = -1;
    { int gr = rowTile*64 + lm; if (gr < cnt) anode = nbucket[start + gr]; }
    const int bj = tid & 63;            // B-load col
    const int bk = (tid >> 6) << 2;     // B-load k base {0,4,8,12}
    const float* Wt = Wb + (size_t)t*HD*HD + colTile*64;

    float acc[4][4] = {};
    for (int k0 = 0; k0 < HD; k0 += 16){
        float4 av = make_float4(0.f,0.f,0.f,0.f);
        if (anode >= 0)
            av = *reinterpret_cast<const float4*>(&in[(size_t)anode*HD + k0 + lk]);
        As[lk+0][lm]=av.x; As[lk+1][lm]=av.y; As[lk+2][lm]=av.z; As[lk+3][lm]=av.w;
        #pragma unroll
        for (int i=0;i<4;i++)
            Bs[bk+i][bj] = Wt[(size_t)(k0+bk+i)*HD + bj];
        __syncthreads();
        #pragma unroll
        for (int kk=0;kk<16;kk++){
            float4 a4 = *reinterpret_cast<const float4*>(&As[kk][ty<<2]);
            float4 b4 = *reinterpret_cast<const float4*>(&Bs[kk][tx<<2]);
            acc[0][0]=fmaf(a4.x,b4.x,acc[0][0]); acc[0][1]=fmaf(a4.x,b4.y,acc[0][1]);
            acc[0][2]=fmaf(a4.x,b4.z,acc[0][2]); acc[0][3]=fmaf(a4.x,b4.w,acc[0][3]);
            acc[1][0]=fmaf(a4.y,b4.x,acc[1][0]); acc[1][1]=fmaf(a4.y,b4.y,acc[1][1]);
            acc[1][2]=fmaf(a4.y,b4.z,acc[1][2]); acc[1][3]=fmaf(a4.y,b4.w,acc[1][3]);
            acc[2][0]=fmaf(a4.z,b4.x,acc[2][0]); acc[2][1]=fmaf(a4.z,b4.y,acc[2][1]);
            acc[2][2]=fmaf(a4.z,b4.z,acc[2][2]); acc[2][3]=fmaf(a4.z,b4.w,acc[2][3]);
            acc[3][0]=fmaf(a4.w,b4.x,acc[3][0]); acc[3][1]=fmaf(a4.w,b4.y,acc[3][1]);
            acc[3][2]=fmaf(a4.w,b4.z,acc[3][2]); acc[3][3]=fmaf(a4.w,b4.w,acc[3][3]);
        }
        __syncthreads();
    }
    float sk = 0.f;
    if (mode == 2) sk = 1.f/(1.f + expf(-skipv[t]));
    const int c0 = colTile*64 + (tx<<2);
    #pragma unroll
    for (int i=0;i<4;i++){
        int gr = rowTile*64 + (ty<<2) + i;
        if (gr >= cnt) continue;
        int node = nbucket[start + gr];
        float4 o;
        o.x = acc[i][0] + bb[t*HD + c0 + 0];
        o.y = acc[i][1] + bb[t*HD + c0 + 1];
        o.z = acc[i][2] + bb[t*HD + c0 + 2];
        o.w = acc[i][3] + bb[t*HD + c0 + 3];
        if (mode == 1){
            o.x = tanhf(o.x); o.y = tanhf(o.y); o.z = tanhf(o.z); o.w = tanhf(o.w);
        } else if (mode == 2){
            const float4 xo = *reinterpret_cast<const float4*>(&xold[(size_t)node*HD + c0]);
            o.x = o.x*sk + xo.x*(1.f-sk);
            o.y = o.y*sk + xo.y*(1.f-sk);
            o.z = o.z*sk + xo.z*(1.f-sk);
            o.w = o.w*sk + xo.w*(1.f-sk);
        }
        *reinterpret_cast<float4*>(&out[(size_t)node*HD + c0]) = o;
    }
}

// ---------- small row GEMM: C[row, ty] = A[row] @ W[ty] (+bias) ----------
__global__ __launch_bounds__(256) void k_row_gemm(
    const float* __restrict__ A, const float* __restrict__ Wb, const float* __restrict__ bias,
    float* __restrict__ C, int c_stride)
{
    const int row = blockIdx.x, ty = blockIdx.y, d = threadIdx.x;
    const float* W = Wb + (size_t)ty*HD*HD;
    __shared__ float ar[HD];
    ar[d] = A[(size_t)row*HD + d];
    __syncthreads();
    float acc = bias ? bias[d] : 0.f;
    #pragma unroll 8
    for (int k=0;k<HD;k++) acc = fmaf(ar[k], W[(size_t)k*HD + d], acc);
    C[(size_t)row*c_stride + ty*HD + d] = acc;
}

// ---------- edge attention scores ----------
__global__ __launch_bounds__(256) void k_edge_att(
    const float* __restrict__ q0, const float* __restrict__ k0, const float* __restrict__ Kc,
    const float* __restrict__ relA, const float* __restrict__ relP,
    const int* __restrict__ ei, const int* __restrict__ etime, const int* __restrict__ ntype,
    const int* __restrict__ ebucket, const int* __restrict__ eoff,
    float* __restrict__ att_e)
{
    const int r = blockIdx.y;
    const int start = eoff[r], cnt = eoff[r+1]-start;
    if ((int)blockIdx.x*64 >= cnt) return;
    const int tid = threadIdx.x;
    const int wave = tid >> 6, lane = tid & 63;
    __shared__ float Ash[NH*DKq*DKq];
    __shared__ float psh[NH];
    __shared__ float rq[4][HD];
    __shared__ float rk[4][HD];
    for (int i = tid; i < NH*DKq*DKq; i += 256) Ash[i] = relA[(size_t)r*NH*DKq*DKq + i];
    if (tid < NH) psh[tid] = relP[r*NH + tid] * INV_SQRT_DK;
    __syncthreads();
    const int h2 = lane >> 5, c = lane & 31;
    const int base = blockIdx.x*64 + wave*16;
    for (int it = 0; it < 16; it++){
        const int idx = base + it;
        if (idx >= cnt) break;
        const int e = ebucket[start + idx];
        const int src = ei[e], tgt = ei[NE + e];
        const int tm = etime[e], st = ntype[src];
        const float* qrow = q0 + (size_t)tgt*HD;
        const float* krow = k0 + (size_t)src*HD;
        const float* crow = Kc + (size_t)(tm*NT + st)*HD;
        #pragma unroll
        for (int i=0;i<4;i++){
            int cc = lane + i*64;
            rq[wave][cc] = qrow[cc];
            rk[wave][cc] = krow[cc] + crow[cc];
        }
        #pragma unroll
        for (int hh=0; hh<4; hh++){
            const int h = hh*2 + h2;
            float kr = 0.f;
            #pragma unroll
            for (int dd=0; dd<DKq; dd++)
                kr = fmaf(Ash[h*DKq*DKq + dd*DKq + c], rk[wave][h*DKq + dd], kr);
            float prod = rq[wave][h*DKq + c] * kr;
            #pragma unroll
            for (int m=16;m>=1;m>>=1) prod += __shfl_xor(prod, m);
            if (c == 0) att_e[(size_t)e*NH + h] = prod * psh[h];
        }
    }
}

// ---------- edge message + aggregation ----------
__global__ __launch_bounds__(256) void k_edge_msg(
    const float* __restrict__ v0, const float* __restrict__ Vc,
    const float* __restrict__ relM, const float* __restrict__ alpha,
    const int* __restrict__ ei, const int* __restrict__ etime, const int* __restrict__ ntype,
    const int* __restrict__ ebucket, const int* __restrict__ eoff,
    float* __restrict__ agg)
{
    const int r = blockIdx.y;
    const int start = eoff[r], cnt = eoff[r+1]-start;
    if ((int)blockIdx.x*64 >= cnt) return;
    const int tid = threadIdx.x;
    const int wave = tid >> 6, lane = tid & 63;
    __shared__ float Msh[NH*DKq*DKq];
    __shared__ float rv[4][HD];
    for (int i = tid; i < NH*DKq*DKq; i += 256) Msh[i] = relM[(size_t)r*NH*DKq*DKq + i];
    __syncthreads();
    const int h2 = lane >> 5, c = lane & 31;
    const int base = blockIdx.x*64 + wave*16;
    for (int it = 0; it < 16; it++){
        const int idx = base + it;
        if (idx >= cnt) break;
        const int e = ebucket[start + idx];
        const int src = ei[e], tgt = ei[NE + e];
        const int tm = etime[e], st = ntype[src];
        const float* vrow = v0 + (size_t)src*HD;
        const float* crow = Vc + (size_t)(tm*NT + st)*HD;
        #pragma unroll
        for (int i=0;i<4;i++){
            int cc = lane + i*64;
            rv[wave][cc] = vrow[cc] + crow[cc];
        }
        #pragma unroll
        for (int hh=0; hh<4; hh++){
            const int h = hh*2 + h2;
            float vr = 0.f;
            #pragma unroll
            for (int dd=0; dd<DKq; dd++)
                vr = fmaf(Msh[h*DKq*DKq + dd*DKq + c], rv[wave][h*DKq + dd], vr);
            float al = alpha[(size_t)e*NH + h];
            atomicAdd(&agg[(size_t)tgt*HD + h*DKq + c], al*vr);
        }
    }
}

// ---------- segment softmax ----------
__global__ void k_seg_max(const float* __restrict__ att_e, const int* __restrict__ ei,
                          unsigned* __restrict__ segmax){
    int i = blockIdx.x*blockDim.x + threadIdx.x;
    if (i >= NE*NH) return;
    int e = i >> 3, h = i & 7;
    atomicMax(&segmax[(size_t)ei[NE+e]*NH + h], f2ord(att_e[i]));
}
__global__ void k_seg_expsum(float* __restrict__ att_e, const int* __restrict__ ei,
                             const unsigned* __restrict__ segmax, float* __restrict__ segsum){
    int i = blockIdx.x*blockDim.x + threadIdx.x;
    if (i >= NE*NH) return;
    int e = i >> 3, h = i & 7;
    int t = ei[NE+e];
    float m = ord2f(segmax[(size_t)t*NH + h]);
    float ex = expf(att_e[i] - m);
    att_e[i] = ex;
    atomicAdd(&segsum[(size_t)t*NH + h], ex);
}
__global__ void k_seg_alpha(const float* __restrict__ att_e, const int* __restrict__ ei,
                            const float* __restrict__ segsum, float* __restrict__ alpha,
                            float* __restrict__ out_att){
    int i = blockIdx.x*blockDim.x + threadIdx.x;
    if (i >= NE*NH) return;
    int e = i >> 3, h = i & 7;
    int t = ei[NE+e];
    float a = att_e[i] / segsum[(size_t)t*NH + h];
    alpha[i] = a;
    if (out_att) out_att[i] = a;
}

// ---------- misc elementwise ----------
__global__ void k_init_seg(unsigned* __restrict__ segmax, float* __restrict__ segsum,
                           float* __restrict__ agg){
    int i = blockIdx.x*blockDim.x + threadIdx.x;
    if (i < NN*HD) agg[i] = 0.f;
    if (i < NN*NH){ segmax[i] = 0u; segsum[i] = 0.f; }
}
__global__ void k_gelu(float* __restrict__ agg){
    int i = blockIdx.x*blockDim.x + threadIdx.x;
    if (i >= NN*HD) return;
    float x = agg[i];
    agg[i] = 0.5f*x*(1.f + erff(x*0.70710678118654752f));
}
__global__ void k_copy(const float* __restrict__ s, float* __restrict__ d, int n){
    int i = blockIdx.x*blockDim.x + threadIdx.x;
    if (i < n) d[i] = s[i];
}

extern "C" void kernel_launch(void* const* d_in, const int* in_sizes, int n_in,
                              void* d_out, int out_size, void* d_ws, size_t ws_size,
                              hipStream_t stream)
{
    const float* node_feature = (const float*)d_in[0];
    const int*   node_type    = (const int*)d_in[1];
    const int*   edge_time    = (const int*)d_in[2];
    const int*   edge_index   = (const int*)d_in[3];  // [2,E]
    const int*   edge_type    = (const int*)d_in[4];
    const float* adapt_W = (const float*)d_in[5];
    const float* adapt_b = (const float*)d_in[6];
    const float* k_W = (const float*)d_in[7];
    const float* k_b = (const float*)d_in[8];
    const float* q_W = (const float*)d_in[9];
    const float* q_b = (const float*)d_in[10];
    const float* v_W = (const float*)d_in[11];
    const float* v_b = (const float*)d_in[12];
    const float* a_W = (const float*)d_in[13];
    const float* a_b = (const float*)d_in[14];
    const float* rel_pri = (const float*)d_in[15];
    const float* rel_att = (const float*)d_in[16];
    const float* rel_msg = (const float*)d_in[17];
    const float* skip  = (const float*)d_in[18];
    const float* rte_W = (const float*)d_in[19];
    const float* rte_b = (const float*)d_in[20];
    const float* rte_emb = (const float*)d_in[21];

    char* wp = (char*)d_ws;
    auto alloc_f = [&](size_t n)->float*{ float* p=(float*)wp; wp += n*sizeof(float); return p; };
    auto alloc_i = [&](size_t n)->int*  { int*   p=(int*)wp;   wp += n*sizeof(int);   return p; };
    float* xA    = alloc_f((size_t)NN*HD);
    float* xB    = alloc_f((size_t)NN*HD);
    float* q0    = alloc_f((size_t)NN*HD);
    float* k0    = alloc_f((size_t)NN*HD);
    float* v0    = alloc_f((size_t)NN*HD);
    float* agg   = alloc_f((size_t)NN*HD);
    float* att_e = alloc_f((size_t)NE*NH);
    float* alpha = alloc_f((size_t)NE*NH);
    float* segsum= alloc_f((size_t)NN*NH);
    float* rteP  = alloc_f((size_t)MAXL*HD);
    float* Kc    = alloc_f((size_t)MAXL*NT*HD);
    float* Vc    = alloc_f((size_t)MAXL*NT*HD);
    unsigned* segmax = (unsigned*)alloc_i((size_t)NN*NH);
    int* nbucket = alloc_i(NN);
    int* ebucket = alloc_i(NE);
    int* nhist = alloc_i(HBLK*NT);
    int* ehist = alloc_i(HBLK*NR);
    int* nbase = alloc_i(HBLK*NT);
    int* ebase = alloc_i(HBLK*NR);
    int* noff = alloc_i(8);  int* eoff = alloc_i(16);

    float* out_att = (float*)d_out;
    float* out_x   = (float*)d_out + (size_t)NE*NH;

    const dim3 gT(4, (NN+63)/64, NT);
    const dim3 gE((NE+63)/64, NR);
    const int gEH = (NE*NH + 255)/256;
    const int gNH = (NN*HD + 255)/256;

    // buckets: block-local histogram radix pass (no global atomics)
    k_hist<<<HBLK,256,0,stream>>>(node_type, edge_type, nhist, ehist);
    k_scan<<<1,64,0,stream>>>(nhist, ehist, noff, eoff, nbase, ebase);
    k_scatter2<<<HBLK,256,0,stream>>>(node_type, edge_type, nbase, ebase, nbucket, ebucket);

    // adapt: x = tanh(node_feature @ adapt_W[t] + b)
    k_typed_gemm<<<gT,256,0,stream>>>(node_feature, adapt_W, adapt_b, xA, nbucket, noff,
                                      1, nullptr, nullptr);

    const float* x_in = xA;
    float* x_out = xB;
    for (int l = 0; l < NL; l++){
        k_row_gemm<<<dim3(MAXL,1),256,0,stream>>>(rte_emb, rte_W + (size_t)l*HD*HD,
                                                  rte_b + (size_t)l*HD, rteP, HD);
        k_row_gemm<<<dim3(MAXL,NT),256,0,stream>>>(rteP, k_W + (size_t)l*NT*HD*HD, nullptr, Kc, NT*HD);
        k_row_gemm<<<dim3(MAXL,NT),256,0,stream>>>(rteP, v_W + (size_t)l*NT*HD*HD, nullptr, Vc, NT*HD);
        k_typed_gemm<<<gT,256,0,stream>>>(x_in, q_W + (size_t)l*NT*HD*HD, q_b + (size_t)l*NT*HD,
                                          q0, nbucket, noff, 0, nullptr, nullptr);
        k_typed_gemm<<<gT,256,0,stream>>>(x_in, k_W + (size_t)l*NT*HD*HD, k_b + (size_t)l*NT*HD,
                                          k0, nbucket, noff, 0, nullptr, nullptr);
        k_typed_gemm<<<gT,256,0,stream>>>(x_in, v_W + (size_t)l*NT*HD*HD, v_b + (size_t)l*NT*HD,
                                          v0, nbucket, noff, 0, nullptr, nullptr);
        k_init_seg<<<gNH,256,0,stream>>>(segmax, segsum, agg);
        k_edge_att<<<gE,256,0,stream>>>(q0, k0, Kc,
                                        rel_att + (size_t)l*NR*NH*DKq*DKq, rel_pri + (size_t)l*NR*NH,
                                        edge_index, edge_time, node_type, ebucket, eoff, att_e);
        k_seg_max<<<gEH,256,0,stream>>>(att_e, edge_index, segmax);
        k_seg_expsum<<<gEH,256,0,stream>>>(att_e, edge_index, segmax, segsum);
        k_seg_alpha<<<gEH,256,0,stream>>>(att_e, edge_index, segsum, alpha,
                                          (l == NL-1) ? out_att : nullptr);
        k_edge_msg<<<gE,256,0,stream>>>(v0, Vc,
                                        rel_msg + (size_t)l*NR*NH*DKq*DKq, alpha,
                                        edge_index, edge_time, node_type, ebucket, eoff, agg);
        k_gelu<<<gNH,256,0,stream>>>(agg);
        k_typed_gemm<<<gT,256,0,stream>>>(agg, a_W + (size_t)l*NT*HD*HD, a_b + (size_t)l*NT*HD,
                                          x_out, nbucket, noff, 2, skip + (size_t)l*NT, x_in);
        float* tmp = (float*)x_in; x_in = x_out; x_out = tmp;
    }
    k_copy<<<gNH,256,0,stream>>>(x_in, out_x, NN*HD);
}